// Round 6
// baseline (120.515 us; speedup 1.0000x reference)
//
#include <hip/hip_runtime.h>

typedef __attribute__((ext_vector_type(4))) float f32x4;
typedef __attribute__((ext_vector_type(8))) short bf16x8;

typedef __attribute__((address_space(3))) unsigned char lds_b;
typedef const __attribute__((address_space(1))) unsigned char glb_b;

__device__ __forceinline__ void gload_lds16(const void* g, void* l) {
  __builtin_amdgcn_global_load_lds((glb_b*)g, (lds_b*)l, 16, 0, 0);
}

__device__ __forceinline__ unsigned short f2bf(float f) {
  union { float f; unsigned int u; } v; v.f = f;
  unsigned int r = v.u + 0x7fffu + ((v.u >> 16) & 1u);
  return (unsigned short)(r >> 16);
}

// ---------------------------------------------------------------------------
// theta_prep: Tg[k][o][f] (XOR-swizzled) = bf16(Theta[k][f][o]). grid 1.
// ---------------------------------------------------------------------------
__global__ __launch_bounds__(256) void theta_prep_k(const float* __restrict__ Theta,
                                                    unsigned short* __restrict__ Tg) {
  const int tid = threadIdx.x;
#pragma unroll
  for (int j = 0; j < 12; ++j) {
    int i = tid + j * 256;              // 0..3071 float4 index
    int k = i >> 10, rr = i & 1023;
    int f = rr >> 4, o0 = (rr & 15) << 2;
    float4 v = *(const float4*)(Theta + ((size_t)(k * 64 + f)) * 64 + o0);
    float vv[4] = {v.x, v.y, v.z, v.w};
#pragma unroll
    for (int jj = 0; jj < 4; ++jj) {
      int o = o0 + jj;
      int byte = k * 8192 + o * 128 + ((((f >> 3) ^ (o & 7)) << 4) | ((f & 7) << 1));
      *(unsigned short*)((char*)Tg + byte) = f2bf(vv[jj]);
    }
  }
}

// ---------------------------------------------------------------------------
// prep_fused: blocks [0,1024) = prep_U; blocks [1024,3072) = prep_A.
//
// prep_U writes U2 in block-private m-tile-major layout:
//   U2[b][k][mt:32][t:12][o:64][mi:16]  (ushort)
// so each block owns a contiguous 72KB region; per (k,t) its 4 waves fill a
// contiguous 2KB span -> L2 assembles full 128B lines from one wave's stores
// (no cross-block partial-line RMW).
// ---------------------------------------------------------------------------
__global__ __launch_bounds__(256) void prep_fused_k(const float* __restrict__ x,
                                                    const float* __restrict__ cheb,
                                                    const float* __restrict__ att,
                                                    const unsigned short* __restrict__ Tg,
                                                    unsigned short* __restrict__ A_ws,
                                                    unsigned short* __restrict__ U_ws) {
  __shared__ __align__(16) char smem[24576];
  const int bid = blockIdx.x;
  const int tid = threadIdx.x;

  if (bid < 1024) {
    // ================= prep_U part =================
    unsigned short* Xl = (unsigned short*)smem;  // [t][m][f] swizzled, 24KB
    const int b = bid >> 5, mt = bid & 31;
    const int m0 = mt * 16;
    const int lane = tid & 63, w = tid >> 6;
    const int c = lane & 15, q = lane >> 4;

    // Theta fragments: 6 coalesced 16B loads (Tg L2-hot from pre-kernel)
    bf16x8 afr[3][2];
#pragma unroll
    for (int k = 0; k < 3; ++k)
#pragma unroll
      for (int h = 0; h < 2; ++h) {
        int g = h * 4 + q;
        afr[k][h] = *(const bf16x8*)((const char*)Tg +
                      k * 8192 + (w * 16 + c) * 128 + (((g ^ (c & 7)) << 4)));
      }

    // stage Xl: x[b, m0..m0+15, :, :], coalesced float4
    const float* xb = x + ((size_t)(b * 512 + m0)) * 768;
#pragma unroll
    for (int j = 0; j < 12; ++j) {
      int i = tid + j * 256;
      int m = i / 192, r = i - m * 192;
      float4 v = *(const float4*)(xb + (size_t)m * 768 + r * 4);
      float vv[4] = {v.x, v.y, v.z, v.w};
#pragma unroll
      for (int jj = 0; jj < 4; ++jj) {
        int e = r * 4 + jj;               // element = f*12 + t
        int f = e / 12, t = e - f * 12;
        int byte = t * 2048 + m * 128 + ((((f >> 3) ^ (m & 7)) << 4) | ((f & 7) << 1));
        *(unsigned short*)((char*)Xl + byte) = f2bf(vv[jj]);
      }
    }
    __syncthreads();

    // main loop: per t, 2 b128 B-frag reads + 6 MFMA + 12 clustered stores
    const int ub0 = w * 256 + q * 64 + c;     // o*16 + mi, o = w*16+q*4+r
    for (int t = 0; t < 12; ++t) {
      bf16x8 bfr[2];
#pragma unroll
      for (int h = 0; h < 2; ++h) {
        int g = h * 4 + q;
        bfr[h] = *(const bf16x8*)((char*)Xl + t * 2048 + c * 128 + (((g ^ (c & 7)) << 4)));
      }
#pragma unroll
      for (int k = 0; k < 3; ++k) {
        f32x4 acc = {0.f, 0.f, 0.f, 0.f};
        acc = __builtin_amdgcn_mfma_f32_16x16x32_bf16(afr[k][0], bfr[0], acc, 0, 0, 0);
        acc = __builtin_amdgcn_mfma_f32_16x16x32_bf16(afr[k][1], bfr[1], acc, 0, 0, 0);
        unsigned short* up = U_ws +
            ((size_t)(((b * 3 + k) * 32 + mt) * 12 + t)) * 1024 + ub0;
#pragma unroll
        for (int r = 0; r < 4; ++r)
          up[r * 16] = f2bf(acc[r]);
      }
    }
  } else {
    // ================= prep_A part =================
    float (*tile)[68] = (float(*)[68])smem;      // 64x68 fp32, 17.4KB
    const int id = bid - 1024;
    const int m0 = (id & 7) * 64, n0 = ((id >> 3) & 7) * 64, b = id >> 6;
    const int rm = tid >> 2;   // 0..63
    const int c4 = tid & 3;    // 0..3
    for (int k = 0; k < 3; ++k) {
      const float* cp = cheb + ((size_t)(k * 512 + m0 + rm)) * 512 + n0 + c4 * 16;
      const float* ap = att  + ((size_t)(b * 512 + m0 + rm)) * 512 + n0 + c4 * 16;
#pragma unroll
      for (int j = 0; j < 4; ++j) {
        float4 cc = *(const float4*)(cp + j * 4);
        float4 aa = *(const float4*)(ap + j * 4);
        float4 p; p.x = cc.x * aa.x; p.y = cc.y * aa.y; p.z = cc.z * aa.z; p.w = cc.w * aa.w;
        *(float4*)&tile[rm][c4 * 16 + j * 4] = p;
      }
      __syncthreads();
      unsigned int pk[8];
#pragma unroll
      for (int i = 0; i < 8; ++i) {
        float v0 = tile[c4 * 16 + 2 * i][rm];
        float v1 = tile[c4 * 16 + 2 * i + 1][rm];
        pk[i] = (unsigned int)f2bf(v0) | ((unsigned int)f2bf(v1) << 16);
      }
      unsigned short* op = A_ws + ((size_t)(b * 512 + n0 + rm)) * 1536 + k * 512 + m0 + c4 * 16;
      uint4 w0; w0.x = pk[0]; w0.y = pk[1]; w0.z = pk[2]; w0.w = pk[3];
      uint4 w1; w1.x = pk[4]; w1.y = pk[5]; w1.z = pk[6]; w1.w = pk[7];
      ((uint4*)op)[0] = w0;
      ((uint4*)op)[1] = w1;
      __syncthreads();
    }
  }
}

// ---------------------------------------------------------------------------
// gemm_k: out[b][n][ot] = relu( sum_{km} A_ws[b][n][km] * U2[b][k][...][m] )
// 128x128 tile, BK=64, 4 waves (2x2), mfma_f32_16x16x32_bf16.
// U2 layout [b][k][mt][t][o][16]; per-lane source address reproduces the same
// LDS tile contents as the old [b][k][ot][m] layout (fragments unchanged).
// global_load_lds width=16 staging; XCD-aware bijective remap (768 wgs).
// ---------------------------------------------------------------------------
__global__ __launch_bounds__(256) void gemm_k(const unsigned short* __restrict__ A_ws,
                                              const unsigned short* __restrict__ U_ws,
                                              float* __restrict__ out) {
  __shared__ unsigned short At[128 * 64];
  __shared__ unsigned short Bt[128 * 64];
  const int hw = blockIdx.x;
  const int logical = (hw & 7) * 96 + (hw >> 3);
  const int b = logical / 24;
  const int rem = logical - b * 24;
  const int nb = (rem / 6) * 128;
  const int otb = (rem % 6) * 128;

  const int tid = threadIdx.x;
  const int lane = tid & 63, w = tid >> 6;
  const int wr = w >> 1, wc = w & 1;
  const int q = lane >> 4;   // 0..3
  const int c = lane & 15;   // 0..15

  const int rl = lane >> 3;            // row within 8-row group (== row&7)
  const int gsrc = (lane & 7) ^ rl;    // pre-swizzled source granule
  const int mi0 = (gsrc & 1) * 8;      // ushort offset within 16-m tile
  const int mtq = gsrc >> 1;           // m-tile offset within 64-m chunk
  f32x4 acc[4][4] = {};

  // hoisted per-issue (o,t) offsets for the U2 source address
  int ot_off[4];
#pragma unroll
  for (int i = 0; i < 4; ++i) {
    int rr = otb + w * 8 + rl + i * 32;   // ot row index
    int o = rr / 12, t = rr - 12 * o;
    ot_off[i] = t * 1024 + o * 16 + mi0;
  }

  const unsigned short* aRow = A_ws + ((size_t)(b * 512 + nb + w * 8 + rl)) * 1536 + gsrc * 8;
  const int ldsRowBase = w * 8 * 64;

  for (int kt = 0; kt < 24; ++kt) {
    const int k = kt >> 3;
    const int mc = kt & 7;
    const unsigned short* uBase =
        U_ws + ((size_t)((b * 3 + k) * 32 + mc * 4 + mtq)) * 12288;
#pragma unroll
    for (int i = 0; i < 4; ++i) {
      gload_lds16(aRow + (size_t)(i * 32) * 1536 + kt * 64, &At[ldsRowBase + i * 32 * 64]);
      gload_lds16(uBase + ot_off[i],                        &Bt[ldsRowBase + i * 32 * 64]);
    }
    __syncthreads();
#pragma unroll
    for (int h = 0; h < 2; ++h) {
      bf16x8 af[4], bfv[4];
#pragma unroll
      for (int mi = 0; mi < 4; ++mi) {
        int row = wr * 64 + mi * 16 + c;
        af[mi] = *(const bf16x8*)&At[row * 64 + (((h * 4 + q) ^ (row & 7)) << 3)];
      }
#pragma unroll
      for (int ni = 0; ni < 4; ++ni) {
        int row = wc * 64 + ni * 16 + c;
        bfv[ni] = *(const bf16x8*)&Bt[row * 64 + (((h * 4 + q) ^ (row & 7)) << 3)];
      }
#pragma unroll
      for (int mi = 0; mi < 4; ++mi)
#pragma unroll
        for (int ni = 0; ni < 4; ++ni)
          acc[mi][ni] = __builtin_amdgcn_mfma_f32_16x16x32_bf16(af[mi], bfv[ni], acc[mi][ni], 0, 0, 0);
    }
    __syncthreads();
  }
#pragma unroll
  for (int mi = 0; mi < 4; ++mi) {
#pragma unroll
    for (int r = 0; r < 4; ++r) {
      int n = nb + wr * 64 + mi * 16 + q * 4 + r;
      float* orow = out + ((size_t)(b * 512 + n)) * 768 + otb + wc * 64 + c;
#pragma unroll
      for (int ni = 0; ni < 4; ++ni)
        orow[ni * 16] = fmaxf(acc[mi][ni][r], 0.f);
    }
  }
}

// ---------------------------------------------------------------------------
// Fallback (exact fp32, no workspace): grid (512 n, 32 b), 256 threads.
// ---------------------------------------------------------------------------
__global__ __launch_bounds__(256) void fallback_k(const float* __restrict__ x,
                                                  const float* __restrict__ cheb,
                                                  const float* __restrict__ att,
                                                  const float* __restrict__ Theta,
                                                  float* __restrict__ out) {
  __shared__ float wsm[3][512];
  __shared__ float z[3][768];
  const int n = blockIdx.x, b = blockIdx.y;
  const int tid = threadIdx.x;
  for (int i = tid; i < 1536; i += 256) {
    int k = i >> 9, m = i & 511;
    wsm[k][m] = cheb[((size_t)(k * 512 + m)) * 512 + n] * att[((size_t)(b * 512 + m)) * 512 + n];
  }
  __syncthreads();
  float a0[3] = {0.f, 0.f, 0.f}, a1[3] = {0.f, 0.f, 0.f}, a2[3] = {0.f, 0.f, 0.f};
  const float* xb = x + (size_t)b * 512 * 768;
  for (int m = 0; m < 512; ++m) {
    float w0 = wsm[0][m], w1 = wsm[1][m], w2 = wsm[2][m];
    float x0 = xb[(size_t)m * 768 + tid];
    float x1 = xb[(size_t)m * 768 + tid + 256];
    float x2 = xb[(size_t)m * 768 + tid + 512];
    a0[0] += w0 * x0; a0[1] += w1 * x0; a0[2] += w2 * x0;
    a1[0] += w0 * x1; a1[1] += w1 * x1; a1[2] += w2 * x1;
    a2[0] += w0 * x2; a2[1] += w1 * x2; a2[2] += w2 * x2;
  }
#pragma unroll
  for (int k = 0; k < 3; ++k) {
    z[k][tid] = a0[k]; z[k][tid + 256] = a1[k]; z[k][tid + 512] = a2[k];
  }
  __syncthreads();
#pragma unroll
  for (int j = 0; j < 3; ++j) {
    int ot = tid + j * 256;
    int o = ot / 12, t = ot - o * 12;
    float s = 0.f;
    for (int k = 0; k < 3; ++k)
#pragma unroll
      for (int f = 0; f < 64; ++f)
        s += z[k][f * 12 + t] * Theta[((size_t)(k * 64 + f)) * 64 + o];
    out[((size_t)(b * 512 + n)) * 768 + ot] = fmaxf(s, 0.f);
  }
}

extern "C" void kernel_launch(void* const* d_in, const int* in_sizes, int n_in,
                              void* d_out, int out_size, void* d_ws, size_t ws_size,
                              hipStream_t stream) {
  const float* x     = (const float*)d_in[0];  // (32,512,64,12)
  const float* cheb  = (const float*)d_in[1];  // (3,512,512)
  const float* att   = (const float*)d_in[2];  // (32,512,512)
  const float* Theta = (const float*)d_in[3];  // (3,64,64)
  float* out = (float*)d_out;                  // (32,512,64,12)

  const size_t needA = (size_t)32 * 512 * 1536 * 2;       // 50,331,648
  const size_t needU = (size_t)32 * 3 * 768 * 512 * 2;    // 75,497,472
  const size_t needT = (size_t)3 * 64 * 64 * 2;           // 24,576

  if (ws_size >= needA + needU + needT) {
    unsigned short* A_ws = (unsigned short*)d_ws;
    unsigned short* U_ws = (unsigned short*)((char*)d_ws + needA);
    unsigned short* Tg   = (unsigned short*)((char*)d_ws + needA + needU);
    theta_prep_k<<<dim3(1), 256, 0, stream>>>(Theta, Tg);
    prep_fused_k<<<dim3(3072), 256, 0, stream>>>(x, cheb, att, Tg, A_ws, U_ws);
    gemm_k<<<dim3(768), 256, 0, stream>>>(A_ws, U_ws, out);
  } else {
    fallback_k<<<dim3(512, 32), 256, 0, stream>>>(x, cheb, att, Theta, out);
  }
}

// Round 7
// 102.817 us; speedup vs baseline: 1.1721x; 1.1721x over previous
//
#include <hip/hip_runtime.h>

typedef __attribute__((ext_vector_type(4))) float f32x4;
typedef __attribute__((ext_vector_type(8))) short bf16x8;

typedef __attribute__((address_space(3))) unsigned char lds_b;
typedef const __attribute__((address_space(1))) unsigned char glb_b;

__device__ __forceinline__ void gload_lds16(const void* g, void* l) {
  __builtin_amdgcn_global_load_lds((glb_b*)g, (lds_b*)l, 16, 0, 0);
}

__device__ __forceinline__ unsigned short f2bf(float f) {
  union { float f; unsigned int u; } v; v.f = f;
  unsigned int r = v.u + 0x7fffu + ((v.u >> 16) & 1u);
  return (unsigned short)(r >> 16);
}

// ---------------------------------------------------------------------------
// theta_prep: Tg[k][o][f] (XOR-swizzled) = bf16(Theta[k][f][o]). grid 1.
// ---------------------------------------------------------------------------
__global__ __launch_bounds__(256) void theta_prep_k(const float* __restrict__ Theta,
                                                    unsigned short* __restrict__ Tg) {
  const int tid = threadIdx.x;
#pragma unroll
  for (int j = 0; j < 12; ++j) {
    int i = tid + j * 256;              // 0..3071 float4 index
    int k = i >> 10, rr = i & 1023;
    int f = rr >> 4, o0 = (rr & 15) << 2;
    float4 v = *(const float4*)(Theta + ((size_t)(k * 64 + f)) * 64 + o0);
    float vv[4] = {v.x, v.y, v.z, v.w};
#pragma unroll
    for (int jj = 0; jj < 4; ++jj) {
      int o = o0 + jj;
      int byte = k * 8192 + o * 128 + ((((f >> 3) ^ (o & 7)) << 4) | ((f & 7) << 1));
      *(unsigned short*)((char*)Tg + byte) = f2bf(vv[jj]);
    }
  }
}

// ---------------------------------------------------------------------------
// prep_fused: blocks [0,1024) = prep_U; blocks [1024,3072) = prep_A.
//
// U3 layout: U3[b][k][mt:32][ot:768][mi:16] (ushort; 24KB per (b,k,mt)).
// Block-private regions (no cross-block lines). A 128B line = 4 consecutive
// ot = same o, t..t+3 -> its 4 sub-rows are stored by the SAME wave in
// adjacent t-iterations => L2 assembles full lines before DRAM.
// ---------------------------------------------------------------------------
__global__ __launch_bounds__(256) void prep_fused_k(const float* __restrict__ x,
                                                    const float* __restrict__ cheb,
                                                    const float* __restrict__ att,
                                                    const unsigned short* __restrict__ Tg,
                                                    unsigned short* __restrict__ A_ws,
                                                    unsigned short* __restrict__ U_ws) {
  __shared__ __align__(16) char smem[24576];
  const int bid = blockIdx.x;
  const int tid = threadIdx.x;

  if (bid < 1024) {
    // ================= prep_U part =================
    unsigned short* Xl = (unsigned short*)smem;  // [t][m][f] swizzled, 24KB
    const int b = bid >> 5, mt = bid & 31;
    const int m0 = mt * 16;
    const int lane = tid & 63, w = tid >> 6;
    const int c = lane & 15, q = lane >> 4;

    // Theta fragments: 6 coalesced 16B loads (Tg L2-hot from pre-kernel)
    bf16x8 afr[3][2];
#pragma unroll
    for (int k = 0; k < 3; ++k)
#pragma unroll
      for (int h = 0; h < 2; ++h) {
        int g = h * 4 + q;
        afr[k][h] = *(const bf16x8*)((const char*)Tg +
                      k * 8192 + (w * 16 + c) * 128 + (((g ^ (c & 7)) << 4)));
      }

    // stage Xl: x[b, m0..m0+15, :, :], coalesced float4
    const float* xb = x + ((size_t)(b * 512 + m0)) * 768;
#pragma unroll
    for (int j = 0; j < 12; ++j) {
      int i = tid + j * 256;
      int m = i / 192, r = i - m * 192;
      float4 v = *(const float4*)(xb + (size_t)m * 768 + r * 4);
      float vv[4] = {v.x, v.y, v.z, v.w};
#pragma unroll
      for (int jj = 0; jj < 4; ++jj) {
        int e = r * 4 + jj;               // element = f*12 + t
        int f = e / 12, t = e - f * 12;
        int byte = t * 2048 + m * 128 + ((((f >> 3) ^ (m & 7)) << 4) | ((f & 7) << 1));
        *(unsigned short*)((char*)Xl + byte) = f2bf(vv[jj]);
      }
    }
    __syncthreads();

    // main loop: per t, 2 b128 B-frag reads + 6 MFMA + stores at (o*12+t)*16+c
    const int oc = (w * 16 + q * 4) * 192 + c;   // o*192 (+r*192) + c
    for (int t = 0; t < 12; ++t) {
      bf16x8 bfr[2];
#pragma unroll
      for (int h = 0; h < 2; ++h) {
        int g = h * 4 + q;
        bfr[h] = *(const bf16x8*)((char*)Xl + t * 2048 + c * 128 + (((g ^ (c & 7)) << 4)));
      }
#pragma unroll
      for (int k = 0; k < 3; ++k) {
        f32x4 acc = {0.f, 0.f, 0.f, 0.f};
        acc = __builtin_amdgcn_mfma_f32_16x16x32_bf16(afr[k][0], bfr[0], acc, 0, 0, 0);
        acc = __builtin_amdgcn_mfma_f32_16x16x32_bf16(afr[k][1], bfr[1], acc, 0, 0, 0);
        unsigned short* up = U_ws +
            ((size_t)((b * 3 + k) * 32 + mt)) * 12288 + t * 16 + oc;
#pragma unroll
        for (int r = 0; r < 4; ++r)
          up[r * 192] = f2bf(acc[r]);
      }
    }
  } else {
    // ================= prep_A part =================
    float (*tile)[68] = (float(*)[68])smem;      // 64x68 fp32, 17.4KB
    const int id = bid - 1024;
    const int m0 = (id & 7) * 64, n0 = ((id >> 3) & 7) * 64, b = id >> 6;
    const int rm = tid >> 2;   // 0..63
    const int c4 = tid & 3;    // 0..3
    for (int k = 0; k < 3; ++k) {
      const float* cp = cheb + ((size_t)(k * 512 + m0 + rm)) * 512 + n0 + c4 * 16;
      const float* ap = att  + ((size_t)(b * 512 + m0 + rm)) * 512 + n0 + c4 * 16;
#pragma unroll
      for (int j = 0; j < 4; ++j) {
        float4 cc = *(const float4*)(cp + j * 4);
        float4 aa = *(const float4*)(ap + j * 4);
        float4 p; p.x = cc.x * aa.x; p.y = cc.y * aa.y; p.z = cc.z * aa.z; p.w = cc.w * aa.w;
        *(float4*)&tile[rm][c4 * 16 + j * 4] = p;
      }
      __syncthreads();
      unsigned int pk[8];
#pragma unroll
      for (int i = 0; i < 8; ++i) {
        float v0 = tile[c4 * 16 + 2 * i][rm];
        float v1 = tile[c4 * 16 + 2 * i + 1][rm];
        pk[i] = (unsigned int)f2bf(v0) | ((unsigned int)f2bf(v1) << 16);
      }
      unsigned short* op = A_ws + ((size_t)(b * 512 + n0 + rm)) * 1536 + k * 512 + m0 + c4 * 16;
      uint4 w0; w0.x = pk[0]; w0.y = pk[1]; w0.z = pk[2]; w0.w = pk[3];
      uint4 w1; w1.x = pk[4]; w1.y = pk[5]; w1.z = pk[6]; w1.w = pk[7];
      ((uint4*)op)[0] = w0;
      ((uint4*)op)[1] = w1;
      __syncthreads();
    }
  }
}

// ---------------------------------------------------------------------------
// gemm_k: out[b][n][ot] = relu( sum_{km} A_ws[b][n][km] * U3[...] )
// 128x128 tile, BK=64, 4 waves (2x2), mfma_f32_16x16x32_bf16.
// U3 [b][k][mt][ot][16]: per issue each mt-region is read as a contiguous
// 256B span (full lines). LDS contents identical to the original layout.
// global_load_lds width=16 staging; XCD-aware bijective remap (768 wgs).
// ---------------------------------------------------------------------------
__global__ __launch_bounds__(256) void gemm_k(const unsigned short* __restrict__ A_ws,
                                              const unsigned short* __restrict__ U_ws,
                                              float* __restrict__ out) {
  __shared__ unsigned short At[128 * 64];
  __shared__ unsigned short Bt[128 * 64];
  const int hw = blockIdx.x;
  const int logical = (hw & 7) * 96 + (hw >> 3);
  const int b = logical / 24;
  const int rem = logical - b * 24;
  const int nb = (rem / 6) * 128;
  const int otb = (rem % 6) * 128;

  const int tid = threadIdx.x;
  const int lane = tid & 63, w = tid >> 6;
  const int wr = w >> 1, wc = w & 1;
  const int q = lane >> 4;   // 0..3
  const int c = lane & 15;   // 0..15

  const int rl = lane >> 3;            // row within 8-row group (== row&7)
  const int gsrc = (lane & 7) ^ rl;    // pre-swizzled source granule
  const int mi0 = (gsrc & 1) * 8;      // ushort offset within 16-m tile
  const int mtq = gsrc >> 1;           // m-tile offset within 64-m chunk
  f32x4 acc[4][4] = {};

  const int uOff = (otb + w * 8 + rl) * 16 + mi0;   // + i*32*16 per issue
  const unsigned short* aRow = A_ws + ((size_t)(b * 512 + nb + w * 8 + rl)) * 1536 + gsrc * 8;
  const int ldsRowBase = w * 8 * 64;

  for (int kt = 0; kt < 24; ++kt) {
    const int k = kt >> 3;
    const int mc = kt & 7;
    const unsigned short* uBase =
        U_ws + ((size_t)((b * 3 + k) * 32 + mc * 4 + mtq)) * 12288 + uOff;
#pragma unroll
    for (int i = 0; i < 4; ++i) {
      gload_lds16(aRow + (size_t)(i * 32) * 1536 + kt * 64, &At[ldsRowBase + i * 32 * 64]);
      gload_lds16(uBase + i * 512,                          &Bt[ldsRowBase + i * 32 * 64]);
    }
    __syncthreads();
#pragma unroll
    for (int h = 0; h < 2; ++h) {
      bf16x8 af[4], bfv[4];
#pragma unroll
      for (int mi = 0; mi < 4; ++mi) {
        int row = wr * 64 + mi * 16 + c;
        af[mi] = *(const bf16x8*)&At[row * 64 + (((h * 4 + q) ^ (row & 7)) << 3)];
      }
#pragma unroll
      for (int ni = 0; ni < 4; ++ni) {
        int row = wc * 64 + ni * 16 + c;
        bfv[ni] = *(const bf16x8*)&Bt[row * 64 + (((h * 4 + q) ^ (row & 7)) << 3)];
      }
#pragma unroll
      for (int mi = 0; mi < 4; ++mi)
#pragma unroll
        for (int ni = 0; ni < 4; ++ni)
          acc[mi][ni] = __builtin_amdgcn_mfma_f32_16x16x32_bf16(af[mi], bfv[ni], acc[mi][ni], 0, 0, 0);
    }
    __syncthreads();
  }
#pragma unroll
  for (int mi = 0; mi < 4; ++mi) {
#pragma unroll
    for (int r = 0; r < 4; ++r) {
      int n = nb + wr * 64 + mi * 16 + q * 4 + r;
      float* orow = out + ((size_t)(b * 512 + n)) * 768 + otb + wc * 64 + c;
#pragma unroll
      for (int ni = 0; ni < 4; ++ni)
        orow[ni * 16] = fmaxf(acc[mi][ni][r], 0.f);
    }
  }
}

// ---------------------------------------------------------------------------
// Fallback (exact fp32, no workspace): grid (512 n, 32 b), 256 threads.
// ---------------------------------------------------------------------------
__global__ __launch_bounds__(256) void fallback_k(const float* __restrict__ x,
                                                  const float* __restrict__ cheb,
                                                  const float* __restrict__ att,
                                                  const float* __restrict__ Theta,
                                                  float* __restrict__ out) {
  __shared__ float wsm[3][512];
  __shared__ float z[3][768];
  const int n = blockIdx.x, b = blockIdx.y;
  const int tid = threadIdx.x;
  for (int i = tid; i < 1536; i += 256) {
    int k = i >> 9, m = i & 511;
    wsm[k][m] = cheb[((size_t)(k * 512 + m)) * 512 + n] * att[((size_t)(b * 512 + m)) * 512 + n];
  }
  __syncthreads();
  float a0[3] = {0.f, 0.f, 0.f}, a1[3] = {0.f, 0.f, 0.f}, a2[3] = {0.f, 0.f, 0.f};
  const float* xb = x + (size_t)b * 512 * 768;
  for (int m = 0; m < 512; ++m) {
    float w0 = wsm[0][m], w1 = wsm[1][m], w2 = wsm[2][m];
    float x0 = xb[(size_t)m * 768 + tid];
    float x1 = xb[(size_t)m * 768 + tid + 256];
    float x2 = xb[(size_t)m * 768 + tid + 512];
    a0[0] += w0 * x0; a0[1] += w1 * x0; a0[2] += w2 * x0;
    a1[0] += w0 * x1; a1[1] += w1 * x1; a1[2] += w2 * x1;
    a2[0] += w0 * x2; a2[1] += w1 * x2; a2[2] += w2 * x2;
  }
#pragma unroll
  for (int k = 0; k < 3; ++k) {
    z[k][tid] = a0[k]; z[k][tid + 256] = a1[k]; z[k][tid + 512] = a2[k];
  }
  __syncthreads();
#pragma unroll
  for (int j = 0; j < 3; ++j) {
    int ot = tid + j * 256;
    int o = ot / 12, t = ot - o * 12;
    float s = 0.f;
    for (int k = 0; k < 3; ++k)
#pragma unroll
      for (int f = 0; f < 64; ++f)
        s += z[k][f * 12 + t] * Theta[((size_t)(k * 64 + f)) * 64 + o];
    out[((size_t)(b * 512 + n)) * 768 + ot] = fmaxf(s, 0.f);
  }
}

extern "C" void kernel_launch(void* const* d_in, const int* in_sizes, int n_in,
                              void* d_out, int out_size, void* d_ws, size_t ws_size,
                              hipStream_t stream) {
  const float* x     = (const float*)d_in[0];  // (32,512,64,12)
  const float* cheb  = (const float*)d_in[1];  // (3,512,512)
  const float* att   = (const float*)d_in[2];  // (32,512,512)
  const float* Theta = (const float*)d_in[3];  // (3,64,64)
  float* out = (float*)d_out;                  // (32,512,64,12)

  const size_t needA = (size_t)32 * 512 * 1536 * 2;       // 50,331,648
  const size_t needU = (size_t)32 * 3 * 768 * 512 * 2;    // 75,497,472
  const size_t needT = (size_t)3 * 64 * 64 * 2;           // 24,576

  if (ws_size >= needA + needU + needT) {
    unsigned short* A_ws = (unsigned short*)d_ws;
    unsigned short* U_ws = (unsigned short*)((char*)d_ws + needA);
    unsigned short* Tg   = (unsigned short*)((char*)d_ws + needA + needU);
    theta_prep_k<<<dim3(1), 256, 0, stream>>>(Theta, Tg);
    prep_fused_k<<<dim3(3072), 256, 0, stream>>>(x, cheb, att, Tg, A_ws, U_ws);
    gemm_k<<<dim3(768), 256, 0, stream>>>(A_ws, U_ws, out);
  } else {
    fallback_k<<<dim3(512, 32), 256, 0, stream>>>(x, cheb, att, Theta, out);
  }
}